// Round 4
// baseline (421.938 us; speedup 1.0000x reference)
//
#include <hip/hip_runtime.h>

// NonLocalBlock3D collapsed form:
//   S[b] = X Xt (256x256), s[b] = rowsum(X)
//   kv   = phi_w S g_wT + (phi_w s) g_bT + phi_b (g_w s)T + N phi_b g_bT
//   M    = W_w kvT theta_w / N   (256x256, per batch, bf16)
//   c    = W_w kvT theta_b / N + W_b
//   out  = x + M x + c
#define NB 2
#define CC 256
#define CI 128
#define NN 65536
#define LDA 72        // 64 + 8 pad (bf16), 144B row stride
#define LDX 264       // 256 + 8 pad (bf16) for out-kernel transposed tile

typedef __bf16 bf16x8 __attribute__((ext_vector_type(8)));
typedef float f32x4 __attribute__((ext_vector_type(4)));

__device__ __forceinline__ unsigned short f2bf(float f) {
  unsigned u = __float_as_uint(f);
  u += 0x7fffu + ((u >> 16) & 1u);   // RNE; inputs finite
  return (unsigned short)(u >> 16);
}

// ---------------- Kernel A: full-tile SYRK, split-K partials (no atomics) ----
// Double-buffered LDS software pipeline: per stage, issue next stage's global
// loads BEFORE the MFMA compute, consume them (cvt+ds_write to the other
// buffer) AFTER — one barrier per stage.
// OPERAND-SWAPPED MFMA: D[gj][gi] == S[gi][gj] (symmetry) -> float4 stores.
// use_partial==0 fallback: atomicAdd into S (needs S pre-zeroed).
__global__ __launch_bounds__(512) void nl3d_syrk2(const float* __restrict__ x,
                                                  float* __restrict__ S,
                                                  float* __restrict__ partials,
                                                  float* __restrict__ svec,
                                                  int kchunk, int use_partial) {
  __shared__ unsigned short lds[2][256 * LDA];   // 2 x 36 KB
  const int tid = threadIdx.x;
  const int lane = tid & 63;
  const int wv = tid >> 6;                    // 0..7
  const int wm = wv & 3, wn = wv >> 2;        // 4x2 wave grid: 64 x 128 per wave
  const int b = blockIdx.y;
  const int kc0 = blockIdx.x * kchunk;

  const float* xb = x + (size_t)b * CC * NN;
  f32x4 acc[4][8];
  const f32x4 zero4 = {0.f, 0.f, 0.f, 0.f};
#pragma unroll
  for (int i = 0; i < 4; ++i)
#pragma unroll
    for (int j = 0; j < 8; ++j) acc[i][j] = zero4;

  float rsum[8];
#pragma unroll
  for (int i = 0; i < 8; ++i) rsum[i] = 0.f;

  const int r0 = tid >> 4;    // 0..31
  const int c4 = tid & 15;
  const int m = lane & 15;
  const int kg = (lane >> 4) * 8;

  const int stages = kchunk >> 6;

  // ---- prologue: stage 0 -> lds[0]
  {
    float4 f[8];
#pragma unroll
    for (int i = 0; i < 8; ++i)
      f[i] = *(const float4*)(xb + (size_t)(r0 + 32 * i) * NN + kc0 + c4 * 4);
#pragma unroll
    for (int i = 0; i < 8; ++i) {
      int row = r0 + 32 * i;
      ushort4 h;
      h.x = f2bf(f[i].x); h.y = f2bf(f[i].y); h.z = f2bf(f[i].z); h.w = f2bf(f[i].w);
      *(ushort4*)&lds[0][row * LDA + c4 * 4] = h;
      rsum[i] += f[i].x + f[i].y + f[i].z + f[i].w;
    }
  }
  __syncthreads();

  int cur = 0;
  for (int s = 0; s < stages; ++s) {
    float4 g[8];
    const bool pf = (s + 1 < stages);
    if (pf) {
      const int kc = kc0 + (s + 1) * 64;
#pragma unroll
      for (int i = 0; i < 8; ++i)
        g[i] = *(const float4*)(xb + (size_t)(r0 + 32 * i) * NN + kc + c4 * 4);
    }

    // ---- compute current buffer (no dependence on g -> loads stay in flight)
    const unsigned short* L = lds[cur];
#pragma unroll
    for (int kk = 0; kk < 2; ++kk) {
      bf16x8 afr[4], bfr[8];
#pragma unroll
      for (int mt = 0; mt < 4; ++mt)
        afr[mt] = *(const bf16x8*)&L[(wm * 64 + mt * 16 + m) * LDA + kk * 32 + kg];
#pragma unroll
      for (int nt = 0; nt < 8; ++nt)
        bfr[nt] = *(const bf16x8*)&L[(wn * 128 + nt * 16 + m) * LDA + kk * 32 + kg];
#pragma unroll
      for (int mt = 0; mt < 4; ++mt)
#pragma unroll
        for (int nt = 0; nt < 8; ++nt)
          acc[mt][nt] = __builtin_amdgcn_mfma_f32_16x16x32_bf16(bfr[nt], afr[mt], acc[mt][nt], 0, 0, 0);
    }

    // ---- consume prefetch: cvt + write to other buffer (vmcnt wait lands here)
    if (pf) {
      unsigned short* Lw = (unsigned short*)lds[cur ^ 1];
#pragma unroll
      for (int i = 0; i < 8; ++i) {
        int row = r0 + 32 * i;
        ushort4 h;
        h.x = f2bf(g[i].x); h.y = f2bf(g[i].y); h.z = f2bf(g[i].z); h.w = f2bf(g[i].w);
        *(ushort4*)&Lw[row * LDA + c4 * 4] = h;
        rsum[i] += g[i].x + g[i].y + g[i].z + g[i].w;
      }
    }
    __syncthreads();
    cur ^= 1;
  }

  // D layout after swap: row (reg-quad) = gj-local, col = gi-local.
  // Value D[gj][gi] = S[gj][gi] = S[gi][gj]  ->  float4 store along gj.
  const int col = lane & 15;          // gi-local
  const int rq = (lane >> 4) * 4;     // gj-local quad base
  if (use_partial) {
    float* dst = partials + ((size_t)(b * gridDim.x + blockIdx.x)) * (CC * CC);
#pragma unroll
    for (int mt = 0; mt < 4; ++mt) {
      const int gi = wm * 64 + mt * 16 + col;
#pragma unroll
      for (int nt = 0; nt < 8; ++nt) {
        const int gj = wn * 128 + nt * 16 + rq;
        float4 v;
        v.x = acc[mt][nt][0]; v.y = acc[mt][nt][1];
        v.z = acc[mt][nt][2]; v.w = acc[mt][nt][3];
        *(float4*)&dst[(size_t)gi * CC + gj] = v;
      }
    }
  } else {
    float* Sb = S + (size_t)b * CC * CC;
#pragma unroll
    for (int mt = 0; mt < 4; ++mt)
#pragma unroll
      for (int nt = 0; nt < 8; ++nt)
#pragma unroll
        for (int r = 0; r < 4; ++r) {
          int gi = wm * 64 + mt * 16 + col;
          int gj = wn * 128 + nt * 16 + rq + r;
          atomicAdd(&Sb[(size_t)gi * CC + gj], acc[mt][nt][r]);
        }
  }

  // rowsums -> svec (small atomics; svec pre-zeroed)
  __syncthreads();
  float* ldsRS = (float*)lds[0];
  if (tid < 256) ldsRS[tid] = 0.f;
  __syncthreads();
#pragma unroll
  for (int i = 0; i < 8; ++i) atomicAdd(&ldsRS[r0 + 32 * i], rsum[i]);
  __syncthreads();
  if (tid < 256) atomicAdd(&svec[b * CC + tid], ldsRS[tid]);
}

// ---------------- partial reduction: S = sum over splits ---------------------
// 256 blocks (full chip) x 128 threads, 4-wide MLP.
__global__ __launch_bounds__(128) void nl3d_reduce(const float* __restrict__ partials,
                                                   float* __restrict__ S, int splits) {
  const int e = blockIdx.x * 128 + threadIdx.x;       // float4 index, 32768 total
  const int b = e >> 14;                              // 16384 float4 per batch
  const int off = e & 16383;
  const float4* p = (const float4*)partials;
  float4 a0 = {0, 0, 0, 0}, a1 = {0, 0, 0, 0}, a2 = {0, 0, 0, 0}, a3 = {0, 0, 0, 0};
  const size_t base = (size_t)b * splits * 16384 + off;
  for (int s = 0; s < splits; s += 4) {
    float4 v0 = p[base + (size_t)s * 16384];
    float4 v1 = p[base + (size_t)(s + 1) * 16384];
    float4 v2 = p[base + (size_t)(s + 2) * 16384];
    float4 v3 = p[base + (size_t)(s + 3) * 16384];
    a0.x += v0.x; a0.y += v0.y; a0.z += v0.z; a0.w += v0.w;
    a1.x += v1.x; a1.y += v1.y; a1.z += v1.z; a1.w += v1.w;
    a2.x += v2.x; a2.y += v2.y; a2.z += v2.z; a2.w += v2.w;
    a3.x += v3.x; a3.y += v3.y; a3.z += v3.z; a3.w += v3.w;
  }
  float4 r;
  r.x = (a0.x + a1.x) + (a2.x + a3.x);
  r.y = (a0.y + a1.y) + (a2.y + a3.y);
  r.z = (a0.z + a1.z) + (a2.z + a3.z);
  r.w = (a0.w + a1.w) + (a2.w + a3.w);
  ((float4*)S)[e] = r;
}

// ---------------- tiny chain kernels (fp32) ----------------------------------
// b1: P = phi_w @ S, with b0's g_w transpose fused in (saves one dispatch).
__global__ void nl3d_b1(const float* __restrict__ phi_w, const float* __restrict__ S,
                        const float* __restrict__ g_w, float* __restrict__ gwT,
                        float* __restrict__ P) {
  // fused b0: each of 256 blocks transposes a 128-element slice of g_w
  if (threadIdx.x < 128) {
    int t = blockIdx.x * 128 + threadIdx.x;   // 32768 total
    int j = t >> 8, d2 = t & 255;
    gwT[d2 * CI + j] = g_w[t];
  }
  int b = blockIdx.x >> 7, i = blockIdx.x & 127, d = threadIdx.x;
  const float* Sb = S + (size_t)b * CC * CC;
  const float* ph = phi_w + i * CC;
  float a0 = 0.f, a1 = 0.f, a2 = 0.f, a3 = 0.f;
  float a4 = 0.f, a5 = 0.f, a6 = 0.f, a7 = 0.f;
  for (int c = 0; c < CC; c += 8) {
    a0 += ph[c + 0] * Sb[(c + 0) * CC + d];
    a1 += ph[c + 1] * Sb[(c + 1) * CC + d];
    a2 += ph[c + 2] * Sb[(c + 2) * CC + d];
    a3 += ph[c + 3] * Sb[(c + 3) * CC + d];
    a4 += ph[c + 4] * Sb[(c + 4) * CC + d];
    a5 += ph[c + 5] * Sb[(c + 5) * CC + d];
    a6 += ph[c + 6] * Sb[(c + 6) * CC + d];
    a7 += ph[c + 7] * Sb[(c + 7) * CC + d];
  }
  P[((size_t)b * CI + i) * CC + d] =
      ((a0 + a1) + (a2 + a3)) + ((a4 + a5) + (a6 + a7));
}

__global__ void nl3d_b2(const float* __restrict__ P, const float* __restrict__ gwT,
                        const float* __restrict__ svec, const float* __restrict__ phi_w,
                        const float* __restrict__ phi_b, const float* __restrict__ g_b,
                        float* __restrict__ kv) {
  int b = blockIdx.x >> 7, i = blockIdx.x & 127, j = threadIdx.x;
  const float* Pr = P + ((size_t)b * CI + i) * CC;
  const float* sv = svec + b * CC;
  const float* ph = phi_w + i * CC;
  float u0 = 0.f, u1 = 0.f, u2 = 0.f, u3 = 0.f;
  for (int c = 0; c < CC; c += 4) {
    u0 += ph[c] * sv[c];
    u1 += ph[c + 1] * sv[c + 1];
    u2 += ph[c + 2] * sv[c + 2];
    u3 += ph[c + 3] * sv[c + 3];
  }
  float a0 = 0.f, a1 = 0.f, a2 = 0.f, a3 = 0.f;
  float v0 = 0.f, v1 = 0.f, v2 = 0.f, v3 = 0.f;
  for (int d = 0; d < CC; d += 4) {
    float gT0 = gwT[d * CI + j],       gT1 = gwT[(d + 1) * CI + j];
    float gT2 = gwT[(d + 2) * CI + j], gT3 = gwT[(d + 3) * CI + j];
    a0 += Pr[d] * gT0;     a1 += Pr[d + 1] * gT1;
    a2 += Pr[d + 2] * gT2; a3 += Pr[d + 3] * gT3;
    v0 += sv[d] * gT0;     v1 += sv[d + 1] * gT1;
    v2 += sv[d + 2] * gT2; v3 += sv[d + 3] * gT3;
  }
  kv[((size_t)b * CI + i) * CI + j] =
      ((a0 + a1) + (a2 + a3)) + ((u0 + u1) + (u2 + u3)) * g_b[j] +
      phi_b[i] * (((v0 + v1) + (v2 + v3)) + (float)NN * g_b[j]);
}

__global__ void nl3d_b3(const float* __restrict__ kv, const float* __restrict__ theta_w,
                        const float* __restrict__ theta_b, float* __restrict__ T2,
                        float* __restrict__ tb2) {
  int b = blockIdx.x >> 7, j = blockIdx.x & 127, c = threadIdx.x;
  const float* kvb = kv + (size_t)b * CI * CI;
  float a0 = 0.f, a1 = 0.f, a2 = 0.f, a3 = 0.f;
  for (int i = 0; i < CI; i += 4) {
    a0 += kvb[i * CI + j] * theta_w[i * CC + c];
    a1 += kvb[(i + 1) * CI + j] * theta_w[(i + 1) * CC + c];
    a2 += kvb[(i + 2) * CI + j] * theta_w[(i + 2) * CC + c];
    a3 += kvb[(i + 3) * CI + j] * theta_w[(i + 3) * CC + c];
  }
  T2[((size_t)b * CI + j) * CC + c] = (a0 + a1) + (a2 + a3);
  if (c == 0) {
    float t = 0.f;
    for (int i = 0; i < CI; ++i) t += kvb[i * CI + j] * theta_b[i];
    tb2[b * CI + j] = t;
  }
}

__global__ void nl3d_b4(const float* __restrict__ T2, const float* __restrict__ tb2,
                        const float* __restrict__ W_w, const float* __restrict__ W_b,
                        unsigned short* __restrict__ Mbf, float* __restrict__ cvec) {
  int b = blockIdx.x >> 8, o = blockIdx.x & 255, c = threadIdx.x;
  const float inv = 1.0f / (float)NN;
  const float* Wr = W_w + o * CI;
  float a0 = 0.f, a1 = 0.f, a2 = 0.f, a3 = 0.f;
  for (int j = 0; j < CI; j += 4) {
    a0 += Wr[j] * T2[((size_t)b * CI + j) * CC + c];
    a1 += Wr[j + 1] * T2[((size_t)b * CI + j + 1) * CC + c];
    a2 += Wr[j + 2] * T2[((size_t)b * CI + j + 2) * CC + c];
    a3 += Wr[j + 3] * T2[((size_t)b * CI + j + 3) * CC + c];
  }
  Mbf[((size_t)b * CC + o) * CC + c] = f2bf(((a0 + a1) + (a2 + a3)) * inv);
  if (c == 0) {
    float t = 0.f;
    for (int j = 0; j < CI; ++j) t += Wr[j] * tb2[b * CI + j];
    cvec[b * CC + o] = t * inv + W_b[o];
  }
}

// ---------------- Kernel C: out = x + M x + c (bf16 MFMA) --------------------
// OPERAND-SWAPPED MFMA (harness-verified in an earlier round): D row-quad lies
// along n (contiguous) -> float4 epilogue, 32 VMEM instrs/thread vs 128, each
// instr covering 16 full 64B lines. NO launch-bounds min-waves: the earlier
// regression was VGPR=64 scratch spills (FETCH/WRITE +40MB), not the epilogue.
// xT staging uses an XOR swizzle on the dword index (bits 2-4 keyed by row>>2)
// to break the 8-way LDS bank conflict of the transposed stores.
__global__ __launch_bounds__(256) void nl3d_out(const float* __restrict__ x,
                                                const unsigned short* __restrict__ Mbf,
                                                const float* __restrict__ cvec,
                                                float* __restrict__ out) {
  __shared__ unsigned short xT[64 * LDX];   // [n-col 0..63][k 0..255] bf16, transposed
  const int tid = threadIdx.x;
  const int lane = tid & 63;
  const int wv = tid >> 6;                  // out-channel group
  const int b = blockIdx.y;
  const int n0 = blockIdx.x * 64;

  const float* xb = x + (size_t)b * CC * NN;
  float* ob = out + (size_t)b * CC * NN;

  {   // stage x[0:256][n0:n0+64] -> transposed bf16 LDS (swizzled dword stores)
    const int c4 = tid & 15;
    const int t4 = tid >> 4;
    float4 f0[8], f1[8];
#pragma unroll
    for (int i = 0; i < 8; ++i) {
      int p = i * 16 + t4;                  // k row-pair 0..127 (= dword index)
      f0[i] = *(const float4*)(xb + (size_t)(2 * p) * NN + n0 + c4 * 4);
      f1[i] = *(const float4*)(xb + (size_t)(2 * p + 1) * NN + n0 + c4 * 4);
    }
#pragma unroll
    for (int i = 0; i < 8; ++i) {
      int p = i * 16 + t4;
      int ps = p ^ ((c4 & 7) << 2);         // swizzle: key = (row>>2)&7, row=c4*4+j
      float a0[4] = {f0[i].x, f0[i].y, f0[i].z, f0[i].w};
      float a1[4] = {f1[i].x, f1[i].y, f1[i].z, f1[i].w};
#pragma unroll
      for (int j = 0; j < 4; ++j) {
        unsigned pack = (unsigned)f2bf(a0[j]) | ((unsigned)f2bf(a1[j]) << 16);
        *(unsigned*)&xT[(c4 * 4 + j) * LDX + 2 * ps] = pack;
      }
    }
  }
  __syncthreads();

  f32x4 acc[4][4];
  const f32x4 zero4 = {0.f, 0.f, 0.f, 0.f};
#pragma unroll
  for (int i = 0; i < 4; ++i)
#pragma unroll
    for (int j = 0; j < 4; ++j) acc[i][j] = zero4;

  const int m = lane & 15;
  const int kg = (lane >> 4) * 8;
  const unsigned short* Mb = Mbf + (size_t)b * CC * CC;

  // software-pipeline the L2-warm M-fragment loads one kc ahead
  bf16x8 afr[4];
#pragma unroll
  for (int mt = 0; mt < 4; ++mt)
    afr[mt] = *(const bf16x8*)(Mb + (size_t)(wv * 64 + mt * 16 + m) * CC + kg);
#pragma unroll
  for (int kc = 0; kc < 8; ++kc) {
    bf16x8 cur[4];
#pragma unroll
    for (int mt = 0; mt < 4; ++mt) cur[mt] = afr[mt];
    if (kc < 7) {
#pragma unroll
      for (int mt = 0; mt < 4; ++mt)
        afr[mt] = *(const bf16x8*)(Mb + (size_t)(wv * 64 + mt * 16 + m) * CC + (kc + 1) * 32 + kg);
    }
    bf16x8 bfr[4];
#pragma unroll
    for (int nt = 0; nt < 4; ++nt) {
      int rr = nt * 16 + m;
      int d0 = (kc * 16 + (kg >> 1)) ^ (((rr >> 2) & 7) << 2);
      bfr[nt] = *(const bf16x8*)&xT[rr * LDX + 2 * d0];
    }
#pragma unroll
    for (int mt = 0; mt < 4; ++mt)
#pragma unroll
      for (int nt = 0; nt < 4; ++nt)
        acc[mt][nt] = __builtin_amdgcn_mfma_f32_16x16x32_bf16(bfr[nt], cur[mt], acc[mt][nt], 0, 0, 0);
  }

  // D layout after swap: row-quad = n-local (contiguous), col = o-local.
  const int colo = lane & 15;          // o-local
  const int rquad = (lane >> 4) * 4;   // n-local quad base
#pragma unroll
  for (int mh = 0; mh < 2; ++mh) {     // mt in pairs: 8 float4 loads in flight
    const int mtA = mh * 2, mtB = mh * 2 + 1;
    const int oA = wv * 64 + mtA * 16 + colo;
    const int oB = wv * 64 + mtB * 16 + colo;
    const float cvA = cvec[b * CC + oA];
    const float cvB = cvec[b * CC + oB];
    const float* xrA = xb + (size_t)oA * NN + n0;
    const float* xrB = xb + (size_t)oB * NN + n0;
    float* orA = ob + (size_t)oA * NN + n0;
    float* orB = ob + (size_t)oB * NN + n0;
    float4 xvA[4], xvB[4];
#pragma unroll
    for (int nt = 0; nt < 4; ++nt) {
      xvA[nt] = *(const float4*)(xrA + nt * 16 + rquad);
      xvB[nt] = *(const float4*)(xrB + nt * 16 + rquad);
    }
#pragma unroll
    for (int nt = 0; nt < 4; ++nt) {
      float4 rA, rB;
      rA.x = xvA[nt].x + acc[mtA][nt][0] + cvA;
      rA.y = xvA[nt].y + acc[mtA][nt][1] + cvA;
      rA.z = xvA[nt].z + acc[mtA][nt][2] + cvA;
      rA.w = xvA[nt].w + acc[mtA][nt][3] + cvA;
      rB.x = xvB[nt].x + acc[mtB][nt][0] + cvB;
      rB.y = xvB[nt].y + acc[mtB][nt][1] + cvB;
      rB.z = xvB[nt].z + acc[mtB][nt][2] + cvB;
      rB.w = xvB[nt].w + acc[mtB][nt][3] + cvB;
      *(float4*)(orA + nt * 16 + rquad) = rA;   // exact fp32 residual
      *(float4*)(orB + nt * 16 + rquad) = rB;
    }
  }
}

extern "C" void kernel_launch(void* const* d_in, const int* in_sizes, int n_in,
                              void* d_out, int out_size, void* d_ws, size_t ws_size,
                              hipStream_t stream) {
  const float* x       = (const float*)d_in[0];
  const float* g_w     = (const float*)d_in[1];
  const float* g_b     = (const float*)d_in[2];
  const float* theta_w = (const float*)d_in[3];
  const float* theta_b = (const float*)d_in[4];
  const float* phi_w   = (const float*)d_in[5];
  const float* phi_b   = (const float*)d_in[6];
  const float* W_w     = (const float*)d_in[7];
  const float* W_b     = (const float*)d_in[8];
  float* out = (float*)d_out;

  char* ws = (char*)d_ws;
  float* S    = (float*)(ws);                         // 2*256*256 f32 = 512 KiB
  float* svec = (float*)(ws + 524288);                // 2*256
  float* P    = (float*)(ws + 526336);                // 2*128*256
  float* gwT  = (float*)(ws + 788480);                // 256*128
  float* kv   = (float*)(ws + 919552);                // 2*128*128
  float* T2   = (float*)(ws + 1050624);               // 2*128*256
  float* tb2  = (float*)(ws + 1312768);               // 2*128
  unsigned short* Mbf = (unsigned short*)(ws + 1313792); // 2*256*256 bf16
  float* cvec = (float*)(ws + 1575936);               // 2*256
  float* partials = (float*)(ws + 2097152);           // NB*splits*256KB

  // pick largest power-of-2 split count whose partials fit in ws
  int splits = 0;
  for (int c = 128; c >= 8; c >>= 1) {
    if (2097152 + (size_t)NB * c * CC * CC * 4 <= ws_size) { splits = c; break; }
  }

  if (splits > 0) {
    hipMemsetAsync(svec, 0, 2048, stream);            // svec only (S via reduce)
    nl3d_syrk2<<<dim3(splits, NB), 512, 0, stream>>>(x, S, partials, svec,
                                                     NN / splits, 1);
    nl3d_reduce<<<256, 128, 0, stream>>>(partials, S, splits);
  } else {
    hipMemsetAsync(ws, 0, 526336, stream);            // S + svec (atomic accum)
    nl3d_syrk2<<<dim3(64, NB), 512, 0, stream>>>(x, S, (float*)ws, svec,
                                                 NN / 64, 0);
  }
  nl3d_b1<<<NB * CI, 256, 0, stream>>>(phi_w, S, g_w, gwT, P);
  nl3d_b2<<<NB * CI, 128, 0, stream>>>(P, gwT, svec, phi_w, phi_b, g_b, kv);
  nl3d_b3<<<NB * CI, 256, 0, stream>>>(kv, theta_w, theta_b, T2, tb2);
  nl3d_b4<<<NB * CC, 256, 0, stream>>>(T2, tb2, W_w, W_b, Mbf, cvec);
  nl3d_out<<<dim3(NN / 64, NB), 256, 0, stream>>>(x, Mbf, cvec, out);
}

// Round 5
// 409.355 us; speedup vs baseline: 1.0307x; 1.0307x over previous
//
#include <hip/hip_runtime.h>

// NonLocalBlock3D collapsed form:
//   S[b] = X Xt (256x256), s[b] = rowsum(X)
//   kv   = phi_w S g_wT + (phi_w s) g_bT + phi_b (g_w s)T + N phi_b g_bT
//   M    = W_w kvT theta_w / N   (256x256, per batch, bf16)
//   c    = W_w kvT theta_b / N + W_b
//   out  = x + M x + c
#define NB 2
#define CC 256
#define CI 128
#define NN 65536
#define LDA 72        // 64 + 8 pad (bf16), 144B row stride
#define LDX 264       // 256 + 8 pad (bf16) for out-kernel transposed tile

typedef __bf16 bf16x8 __attribute__((ext_vector_type(8)));
typedef float f32x4 __attribute__((ext_vector_type(4)));

__device__ __forceinline__ unsigned short f2bf(float f) {
  unsigned u = __float_as_uint(f);
  u += 0x7fffu + ((u >> 16) & 1u);   // RNE; inputs finite
  return (unsigned short)(u >> 16);
}

// ---------------- Kernel A: full-tile SYRK, split-K partials (no atomics) ----
// Double-buffered LDS software pipeline: per stage, issue next stage's global
// loads BEFORE the MFMA compute, consume them (cvt+ds_write to the other
// buffer) AFTER — one barrier per stage.
// OPERAND-SWAPPED MFMA: D[gj][gi] == S[gi][gj] (symmetry) -> float4 stores.
// use_partial==0 fallback: atomicAdd into S (needs S pre-zeroed).
__global__ __launch_bounds__(512) void nl3d_syrk2(const float* __restrict__ x,
                                                  float* __restrict__ S,
                                                  float* __restrict__ partials,
                                                  float* __restrict__ svec,
                                                  int kchunk, int use_partial) {
  __shared__ unsigned short lds[2][256 * LDA];   // 2 x 36 KB
  const int tid = threadIdx.x;
  const int lane = tid & 63;
  const int wv = tid >> 6;                    // 0..7
  const int wm = wv & 3, wn = wv >> 2;        // 4x2 wave grid: 64 x 128 per wave
  const int b = blockIdx.y;
  const int kc0 = blockIdx.x * kchunk;

  const float* xb = x + (size_t)b * CC * NN;
  f32x4 acc[4][8];
  const f32x4 zero4 = {0.f, 0.f, 0.f, 0.f};
#pragma unroll
  for (int i = 0; i < 4; ++i)
#pragma unroll
    for (int j = 0; j < 8; ++j) acc[i][j] = zero4;

  float rsum[8];
#pragma unroll
  for (int i = 0; i < 8; ++i) rsum[i] = 0.f;

  const int r0 = tid >> 4;    // 0..31
  const int c4 = tid & 15;
  const int m = lane & 15;
  const int kg = (lane >> 4) * 8;

  const int stages = kchunk >> 6;

  // ---- prologue: stage 0 -> lds[0]
  {
    float4 f[8];
#pragma unroll
    for (int i = 0; i < 8; ++i)
      f[i] = *(const float4*)(xb + (size_t)(r0 + 32 * i) * NN + kc0 + c4 * 4);
#pragma unroll
    for (int i = 0; i < 8; ++i) {
      int row = r0 + 32 * i;
      ushort4 h;
      h.x = f2bf(f[i].x); h.y = f2bf(f[i].y); h.z = f2bf(f[i].z); h.w = f2bf(f[i].w);
      *(ushort4*)&lds[0][row * LDA + c4 * 4] = h;
      rsum[i] += f[i].x + f[i].y + f[i].z + f[i].w;
    }
  }
  __syncthreads();

  int cur = 0;
  for (int s = 0; s < stages; ++s) {
    float4 g[8];
    const bool pf = (s + 1 < stages);
    if (pf) {
      const int kc = kc0 + (s + 1) * 64;
#pragma unroll
      for (int i = 0; i < 8; ++i)
        g[i] = *(const float4*)(xb + (size_t)(r0 + 32 * i) * NN + kc + c4 * 4);
    }

    // ---- compute current buffer (no dependence on g -> loads stay in flight)
    const unsigned short* L = lds[cur];
#pragma unroll
    for (int kk = 0; kk < 2; ++kk) {
      bf16x8 afr[4], bfr[8];
#pragma unroll
      for (int mt = 0; mt < 4; ++mt)
        afr[mt] = *(const bf16x8*)&L[(wm * 64 + mt * 16 + m) * LDA + kk * 32 + kg];
#pragma unroll
      for (int nt = 0; nt < 8; ++nt)
        bfr[nt] = *(const bf16x8*)&L[(wn * 128 + nt * 16 + m) * LDA + kk * 32 + kg];
#pragma unroll
      for (int mt = 0; mt < 4; ++mt)
#pragma unroll
        for (int nt = 0; nt < 8; ++nt)
          acc[mt][nt] = __builtin_amdgcn_mfma_f32_16x16x32_bf16(bfr[nt], afr[mt], acc[mt][nt], 0, 0, 0);
    }

    // ---- consume prefetch: cvt + write to other buffer (vmcnt wait lands here)
    if (pf) {
      unsigned short* Lw = (unsigned short*)lds[cur ^ 1];
#pragma unroll
      for (int i = 0; i < 8; ++i) {
        int row = r0 + 32 * i;
        ushort4 h;
        h.x = f2bf(g[i].x); h.y = f2bf(g[i].y); h.z = f2bf(g[i].z); h.w = f2bf(g[i].w);
        *(ushort4*)&Lw[row * LDA + c4 * 4] = h;
        rsum[i] += g[i].x + g[i].y + g[i].z + g[i].w;
      }
    }
    __syncthreads();
    cur ^= 1;
  }

  // D layout after swap: row (reg-quad) = gj-local, col = gi-local.
  // Value D[gj][gi] = S[gj][gi] = S[gi][gj]  ->  float4 store along gj.
  const int col = lane & 15;          // gi-local
  const int rq = (lane >> 4) * 4;     // gj-local quad base
  if (use_partial) {
    float* dst = partials + ((size_t)(b * gridDim.x + blockIdx.x)) * (CC * CC);
#pragma unroll
    for (int mt = 0; mt < 4; ++mt) {
      const int gi = wm * 64 + mt * 16 + col;
#pragma unroll
      for (int nt = 0; nt < 8; ++nt) {
        const int gj = wn * 128 + nt * 16 + rq;
        float4 v;
        v.x = acc[mt][nt][0]; v.y = acc[mt][nt][1];
        v.z = acc[mt][nt][2]; v.w = acc[mt][nt][3];
        *(float4*)&dst[(size_t)gi * CC + gj] = v;
      }
    }
  } else {
    float* Sb = S + (size_t)b * CC * CC;
#pragma unroll
    for (int mt = 0; mt < 4; ++mt)
#pragma unroll
      for (int nt = 0; nt < 8; ++nt)
#pragma unroll
        for (int r = 0; r < 4; ++r) {
          int gi = wm * 64 + mt * 16 + col;
          int gj = wn * 128 + nt * 16 + rq + r;
          atomicAdd(&Sb[(size_t)gi * CC + gj], acc[mt][nt][r]);
        }
  }

  // rowsums -> svec (small atomics; svec pre-zeroed)
  __syncthreads();
  float* ldsRS = (float*)lds[0];
  if (tid < 256) ldsRS[tid] = 0.f;
  __syncthreads();
#pragma unroll
  for (int i = 0; i < 8; ++i) atomicAdd(&ldsRS[r0 + 32 * i], rsum[i]);
  __syncthreads();
  if (tid < 256) atomicAdd(&svec[b * CC + tid], ldsRS[tid]);
}

// ---------------- partial reduction: S = sum over splits ---------------------
// 256 blocks (full chip) x 128 threads, 4-wide MLP.
__global__ __launch_bounds__(128) void nl3d_reduce(const float* __restrict__ partials,
                                                   float* __restrict__ S, int splits) {
  const int e = blockIdx.x * 128 + threadIdx.x;       // float4 index, 32768 total
  const int b = e >> 14;                              // 16384 float4 per batch
  const int off = e & 16383;
  const float4* p = (const float4*)partials;
  float4 a0 = {0, 0, 0, 0}, a1 = {0, 0, 0, 0}, a2 = {0, 0, 0, 0}, a3 = {0, 0, 0, 0};
  const size_t base = (size_t)b * splits * 16384 + off;
  for (int s = 0; s < splits; s += 4) {
    float4 v0 = p[base + (size_t)s * 16384];
    float4 v1 = p[base + (size_t)(s + 1) * 16384];
    float4 v2 = p[base + (size_t)(s + 2) * 16384];
    float4 v3 = p[base + (size_t)(s + 3) * 16384];
    a0.x += v0.x; a0.y += v0.y; a0.z += v0.z; a0.w += v0.w;
    a1.x += v1.x; a1.y += v1.y; a1.z += v1.z; a1.w += v1.w;
    a2.x += v2.x; a2.y += v2.y; a2.z += v2.z; a2.w += v2.w;
    a3.x += v3.x; a3.y += v3.y; a3.z += v3.z; a3.w += v3.w;
  }
  float4 r;
  r.x = (a0.x + a1.x) + (a2.x + a3.x);
  r.y = (a0.y + a1.y) + (a2.y + a3.y);
  r.z = (a0.z + a1.z) + (a2.z + a3.z);
  r.w = (a0.w + a1.w) + (a2.w + a3.w);
  ((float4*)S)[e] = r;
}

// ---------------- fused b1+b2: P-row in LDS, kv out --------------------------
// Block (b,i): phase 1 computes P[i][:] = phi_w[i,:] @ S[b] into LDS (256 thr),
// phase 2 computes kv[b][i][:] (128 thr) reading g_w row-major directly
// (gwT transpose eliminated). u/v terms folded in per original b2 formula.
__global__ __launch_bounds__(256) void nl3d_b12(const float* __restrict__ phi_w,
                                                const float* __restrict__ S,
                                                const float* __restrict__ svec,
                                                const float* __restrict__ g_w,
                                                const float* __restrict__ phi_b,
                                                const float* __restrict__ g_b,
                                                float* __restrict__ kv) {
  __shared__ float Prow[CC];
  __shared__ float svl[CC];
  const int b = blockIdx.x >> 7, i = blockIdx.x & 127;
  const int d = threadIdx.x;
  const float* Sb = S + (size_t)b * CC * CC;
  const float* ph = phi_w + i * CC;
  float a0 = 0.f, a1 = 0.f, a2 = 0.f, a3 = 0.f;
  float a4 = 0.f, a5 = 0.f, a6 = 0.f, a7 = 0.f;
  for (int c = 0; c < CC; c += 8) {
    a0 += ph[c + 0] * Sb[(c + 0) * CC + d];
    a1 += ph[c + 1] * Sb[(c + 1) * CC + d];
    a2 += ph[c + 2] * Sb[(c + 2) * CC + d];
    a3 += ph[c + 3] * Sb[(c + 3) * CC + d];
    a4 += ph[c + 4] * Sb[(c + 4) * CC + d];
    a5 += ph[c + 5] * Sb[(c + 5) * CC + d];
    a6 += ph[c + 6] * Sb[(c + 6) * CC + d];
    a7 += ph[c + 7] * Sb[(c + 7) * CC + d];
  }
  Prow[d] = ((a0 + a1) + (a2 + a3)) + ((a4 + a5) + (a6 + a7));
  svl[d] = svec[b * CC + d];
  __syncthreads();

  if (d < CI) {
    const int j = d;
    const float* gr = g_w + (size_t)j * CC;     // row-major along inner dim
    float p0 = 0.f, p1 = 0.f, p2 = 0.f, p3 = 0.f;
    float v0 = 0.f, v1 = 0.f, v2 = 0.f, v3 = 0.f;
    float u0 = 0.f, u1 = 0.f, u2 = 0.f, u3 = 0.f;
    for (int c = 0; c < CC; c += 4) {
      float g0 = gr[c], g1 = gr[c + 1], g2 = gr[c + 2], g3 = gr[c + 3];
      p0 += Prow[c] * g0;     p1 += Prow[c + 1] * g1;
      p2 += Prow[c + 2] * g2; p3 += Prow[c + 3] * g3;
      v0 += svl[c] * g0;      v1 += svl[c + 1] * g1;
      v2 += svl[c + 2] * g2;  v3 += svl[c + 3] * g3;
      u0 += ph[c] * svl[c];       u1 += ph[c + 1] * svl[c + 1];
      u2 += ph[c + 2] * svl[c + 2]; u3 += ph[c + 3] * svl[c + 3];
    }
    float a = (p0 + p1) + (p2 + p3);
    float v = (v0 + v1) + (v2 + v3);
    float u = (u0 + u1) + (u2 + u3);
    kv[((size_t)b * CI + i) * CI + j] =
        a + u * g_b[j] + phi_b[i] * (v + (float)NN * g_b[j]);
  }
}

__global__ void nl3d_b3(const float* __restrict__ kv, const float* __restrict__ theta_w,
                        const float* __restrict__ theta_b, float* __restrict__ T2,
                        float* __restrict__ tb2) {
  int b = blockIdx.x >> 7, j = blockIdx.x & 127, c = threadIdx.x;
  const float* kvb = kv + (size_t)b * CI * CI;
  float a0 = 0.f, a1 = 0.f, a2 = 0.f, a3 = 0.f;
  for (int i = 0; i < CI; i += 4) {
    a0 += kvb[i * CI + j] * theta_w[i * CC + c];
    a1 += kvb[(i + 1) * CI + j] * theta_w[(i + 1) * CC + c];
    a2 += kvb[(i + 2) * CI + j] * theta_w[(i + 2) * CC + c];
    a3 += kvb[(i + 3) * CI + j] * theta_w[(i + 3) * CC + c];
  }
  T2[((size_t)b * CI + j) * CC + c] = (a0 + a1) + (a2 + a3);
  if (c == 0) {
    float t = 0.f;
    for (int i = 0; i < CI; ++i) t += kvb[i * CI + j] * theta_b[i];
    tb2[b * CI + j] = t;
  }
}

__global__ void nl3d_b4(const float* __restrict__ T2, const float* __restrict__ tb2,
                        const float* __restrict__ W_w, const float* __restrict__ W_b,
                        unsigned short* __restrict__ Mbf, float* __restrict__ cvec) {
  int b = blockIdx.x >> 8, o = blockIdx.x & 255, c = threadIdx.x;
  const float inv = 1.0f / (float)NN;
  const float* Wr = W_w + o * CI;
  float a0 = 0.f, a1 = 0.f, a2 = 0.f, a3 = 0.f;
  for (int j = 0; j < CI; j += 4) {
    a0 += Wr[j] * T2[((size_t)b * CI + j) * CC + c];
    a1 += Wr[j + 1] * T2[((size_t)b * CI + j + 1) * CC + c];
    a2 += Wr[j + 2] * T2[((size_t)b * CI + j + 2) * CC + c];
    a3 += Wr[j + 3] * T2[((size_t)b * CI + j + 3) * CC + c];
  }
  Mbf[((size_t)b * CC + o) * CC + c] = f2bf(((a0 + a1) + (a2 + a3)) * inv);
  if (c == 0) {
    float t = 0.f;
    for (int j = 0; j < CI; ++j) t += Wr[j] * tb2[b * CI + j];
    cvec[b * CC + o] = t * inv + W_b[o];
  }
}

// ---------------- Kernel C: out = x + M x + c (bf16 MFMA) --------------------
// v3: same 256x64 tile and LDS (33792B) but 512 threads / 8 waves
// (4 o-groups x 2 n-halves) -> ~2x resident waves per CU, doubling HBM duty
// cycle, with per-XCD stage-to-epilogue footprint unchanged (L2-safe).
// Scalar epilogue kept: quarter-wave = 16 lanes x 4B consecutive = full 64B
// line (the float4-across-rows variant partial-line-writes and RMW-amplifies).
// xT staging uses an XOR swizzle on the dword index (bits 2-4 keyed by row>>2)
// to break the 8-way LDS bank conflict of the transposed stores.
__global__ __launch_bounds__(512) void nl3d_out(const float* __restrict__ x,
                                                const unsigned short* __restrict__ Mbf,
                                                const float* __restrict__ cvec,
                                                float* __restrict__ out) {
  __shared__ unsigned short xT[64 * LDX];   // [n-col 0..63][k 0..255] bf16, transposed
  const int tid = threadIdx.x;
  const int lane = tid & 63;
  const int wv = tid >> 6;                  // 0..7
  const int wm = wv & 3;                    // o-group (64 rows)
  const int wn = wv >> 2;                   // n-half (32 cols)
  const int b = blockIdx.y;
  const int n0 = blockIdx.x * 64;

  const float* xb = x + (size_t)b * CC * NN;
  float* ob = out + (size_t)b * CC * NN;

  {   // stage x[0:256][n0:n0+64] -> transposed bf16 LDS (swizzled dword stores)
    const int c4 = tid & 15;
    const int t4 = tid >> 4;                // 0..31
    float4 f0[4], f1[4];
#pragma unroll
    for (int i = 0; i < 4; ++i) {
      int p = i * 32 + t4;                  // k row-pair 0..127 (= dword index)
      f0[i] = *(const float4*)(xb + (size_t)(2 * p) * NN + n0 + c4 * 4);
      f1[i] = *(const float4*)(xb + (size_t)(2 * p + 1) * NN + n0 + c4 * 4);
    }
#pragma unroll
    for (int i = 0; i < 4; ++i) {
      int p = i * 32 + t4;
      int ps = p ^ ((c4 & 7) << 2);         // swizzle: key = (row>>2)&7, row=c4*4+j
      float a0[4] = {f0[i].x, f0[i].y, f0[i].z, f0[i].w};
      float a1[4] = {f1[i].x, f1[i].y, f1[i].z, f1[i].w};
#pragma unroll
      for (int j = 0; j < 4; ++j) {
        unsigned pack = (unsigned)f2bf(a0[j]) | ((unsigned)f2bf(a1[j]) << 16);
        *(unsigned*)&xT[(c4 * 4 + j) * LDX + 2 * ps] = pack;
      }
    }
  }
  __syncthreads();

  f32x4 acc[4][2];
  const f32x4 zero4 = {0.f, 0.f, 0.f, 0.f};
#pragma unroll
  for (int i = 0; i < 4; ++i)
#pragma unroll
    for (int j = 0; j < 2; ++j) acc[i][j] = zero4;

  const int m = lane & 15;
  const int kg = (lane >> 4) * 8;
  const unsigned short* Mb = Mbf + (size_t)b * CC * CC;
#pragma unroll
  for (int kc = 0; kc < 8; ++kc) {
    bf16x8 afr[4], bfr[2];
#pragma unroll
    for (int mt = 0; mt < 4; ++mt)
      afr[mt] = *(const bf16x8*)(Mb + (size_t)(wm * 64 + mt * 16 + m) * CC + kc * 32 + kg);
#pragma unroll
    for (int nt = 0; nt < 2; ++nt) {
      int rr = wn * 32 + nt * 16 + m;
      int d0 = (kc * 16 + (kg >> 1)) ^ (((rr >> 2) & 7) << 2);
      bfr[nt] = *(const bf16x8*)&xT[rr * LDX + 2 * d0];
    }
#pragma unroll
    for (int mt = 0; mt < 4; ++mt)
#pragma unroll
      for (int nt = 0; nt < 2; ++nt)
        acc[mt][nt] = __builtin_amdgcn_mfma_f32_16x16x32_bf16(afr[mt], bfr[nt], acc[mt][nt], 0, 0, 0);
  }

  const int col = lane & 15;
  const int rquad = (lane >> 4) * 4;
#pragma unroll
  for (int mt = 0; mt < 4; ++mt)
#pragma unroll
    for (int r = 0; r < 4; ++r) {
      int o = wm * 64 + mt * 16 + rquad + r;
      float cv = cvec[b * CC + o];
      const float* xrow = xb + (size_t)o * NN + n0;
      float* orow = ob + (size_t)o * NN + n0;
#pragma unroll
      for (int nt = 0; nt < 2; ++nt) {
        int n = wn * 32 + nt * 16 + col;
        orow[n] = xrow[n] + acc[mt][nt][r] + cv;   // exact fp32 residual
      }
    }
}

extern "C" void kernel_launch(void* const* d_in, const int* in_sizes, int n_in,
                              void* d_out, int out_size, void* d_ws, size_t ws_size,
                              hipStream_t stream) {
  const float* x       = (const float*)d_in[0];
  const float* g_w     = (const float*)d_in[1];
  const float* g_b     = (const float*)d_in[2];
  const float* theta_w = (const float*)d_in[3];
  const float* theta_b = (const float*)d_in[4];
  const float* phi_w   = (const float*)d_in[5];
  const float* phi_b   = (const float*)d_in[6];
  const float* W_w     = (const float*)d_in[7];
  const float* W_b     = (const float*)d_in[8];
  float* out = (float*)d_out;

  char* ws = (char*)d_ws;
  float* S    = (float*)(ws);                         // 2*256*256 f32 = 512 KiB
  float* svec = (float*)(ws + 524288);                // 2*256
  float* kv   = (float*)(ws + 919552);                // 2*128*128
  float* T2   = (float*)(ws + 1050624);               // 2*128*256
  float* tb2  = (float*)(ws + 1312768);               // 2*128
  unsigned short* Mbf = (unsigned short*)(ws + 1313792); // 2*256*256 bf16
  float* cvec = (float*)(ws + 1575936);               // 2*256
  float* partials = (float*)(ws + 2097152);           // NB*splits*256KB

  // pick largest power-of-2 split count whose partials fit in ws
  int splits = 0;
  for (int c = 128; c >= 8; c >>= 1) {
    if (2097152 + (size_t)NB * c * CC * CC * 4 <= ws_size) { splits = c; break; }
  }

  if (splits > 0) {
    hipMemsetAsync(svec, 0, 2048, stream);            // svec only (S via reduce)
    nl3d_syrk2<<<dim3(splits, NB), 512, 0, stream>>>(x, S, partials, svec,
                                                     NN / splits, 1);
    nl3d_reduce<<<256, 128, 0, stream>>>(partials, S, splits);
  } else {
    hipMemsetAsync(ws, 0, 526336, stream);            // S + svec (atomic accum)
    nl3d_syrk2<<<dim3(64, NB), 512, 0, stream>>>(x, S, (float*)ws, svec,
                                                 NN / 64, 0);
  }
  nl3d_b12<<<NB * CI, 256, 0, stream>>>(phi_w, S, svec, g_w, phi_b, g_b, kv);
  nl3d_b3<<<NB * CI, 256, 0, stream>>>(kv, theta_w, theta_b, T2, tb2);
  nl3d_b4<<<NB * CC, 256, 0, stream>>>(T2, tb2, W_w, W_b, Mbf, cvec);
  nl3d_out<<<dim3(NN / 64, NB), 512, 0, stream>>>(x, Mbf, cvec, out);
}

// Round 6
// 381.288 us; speedup vs baseline: 1.1066x; 1.0736x over previous
//
#include <hip/hip_runtime.h>

// NonLocalBlock3D collapsed form:
//   S[b] = X Xt (256x256), s[b] = rowsum(X)
//   kv   = phi_w S g_wT + (phi_w s) g_bT + phi_b (g_w s)T + N phi_b g_bT
//   M    = W_w kvT theta_w / N   (256x256, per batch, bf16)
//   c    = W_w kvT theta_b / N + W_b
//   out  = x + M x + c
#define NB 2
#define CC 256
#define CI 128
#define NN 65536
#define LDA 72        // 64 + 8 pad (bf16), 144B row stride
#define LDX 264       // 256 + 8 pad (bf16) for out-kernel transposed tile
#define LDSW 68       // 64 + 4 pad (f32) epilogue bounce stride: conflict-free

typedef __bf16 bf16x8 __attribute__((ext_vector_type(8)));
typedef float f32x4 __attribute__((ext_vector_type(4)));

__device__ __forceinline__ unsigned short f2bf(float f) {
  unsigned u = __float_as_uint(f);
  u += 0x7fffu + ((u >> 16) & 1u);   // RNE; inputs finite
  return (unsigned short)(u >> 16);
}

// ---------------- Kernel A: full-tile SYRK, split-K partials (no atomics) ----
// Double-buffered LDS software pipeline: per stage, issue next stage's global
// loads BEFORE the MFMA compute, consume them (cvt+ds_write to the other
// buffer) AFTER — one barrier per stage.
// OPERAND-SWAPPED MFMA: D[gj][gi] == S[gi][gj] (symmetry) -> float4 stores.
// use_partial==0 fallback: atomicAdd into S (needs S pre-zeroed).
__global__ __launch_bounds__(512) void nl3d_syrk2(const float* __restrict__ x,
                                                  float* __restrict__ S,
                                                  float* __restrict__ partials,
                                                  float* __restrict__ svec,
                                                  int kchunk, int use_partial) {
  __shared__ unsigned short lds[2][256 * LDA];   // 2 x 36 KB
  const int tid = threadIdx.x;
  const int lane = tid & 63;
  const int wv = tid >> 6;                    // 0..7
  const int wm = wv & 3, wn = wv >> 2;        // 4x2 wave grid: 64 x 128 per wave
  const int b = blockIdx.y;
  const int kc0 = blockIdx.x * kchunk;

  const float* xb = x + (size_t)b * CC * NN;
  f32x4 acc[4][8];
  const f32x4 zero4 = {0.f, 0.f, 0.f, 0.f};
#pragma unroll
  for (int i = 0; i < 4; ++i)
#pragma unroll
    for (int j = 0; j < 8; ++j) acc[i][j] = zero4;

  float rsum[8];
#pragma unroll
  for (int i = 0; i < 8; ++i) rsum[i] = 0.f;

  const int r0 = tid >> 4;    // 0..31
  const int c4 = tid & 15;
  const int m = lane & 15;
  const int kg = (lane >> 4) * 8;

  const int stages = kchunk >> 6;

  // ---- prologue: stage 0 -> lds[0]
  {
    float4 f[8];
#pragma unroll
    for (int i = 0; i < 8; ++i)
      f[i] = *(const float4*)(xb + (size_t)(r0 + 32 * i) * NN + kc0 + c4 * 4);
#pragma unroll
    for (int i = 0; i < 8; ++i) {
      int row = r0 + 32 * i;
      ushort4 h;
      h.x = f2bf(f[i].x); h.y = f2bf(f[i].y); h.z = f2bf(f[i].z); h.w = f2bf(f[i].w);
      *(ushort4*)&lds[0][row * LDA + c4 * 4] = h;
      rsum[i] += f[i].x + f[i].y + f[i].z + f[i].w;
    }
  }
  __syncthreads();

  int cur = 0;
  for (int s = 0; s < stages; ++s) {
    float4 g[8];
    const bool pf = (s + 1 < stages);
    if (pf) {
      const int kc = kc0 + (s + 1) * 64;
#pragma unroll
      for (int i = 0; i < 8; ++i)
        g[i] = *(const float4*)(xb + (size_t)(r0 + 32 * i) * NN + kc + c4 * 4);
    }

    // ---- compute current buffer (no dependence on g -> loads stay in flight)
    const unsigned short* L = lds[cur];
#pragma unroll
    for (int kk = 0; kk < 2; ++kk) {
      bf16x8 afr[4], bfr[8];
#pragma unroll
      for (int mt = 0; mt < 4; ++mt)
        afr[mt] = *(const bf16x8*)&L[(wm * 64 + mt * 16 + m) * LDA + kk * 32 + kg];
#pragma unroll
      for (int nt = 0; nt < 8; ++nt)
        bfr[nt] = *(const bf16x8*)&L[(wn * 128 + nt * 16 + m) * LDA + kk * 32 + kg];
#pragma unroll
      for (int mt = 0; mt < 4; ++mt)
#pragma unroll
        for (int nt = 0; nt < 8; ++nt)
          acc[mt][nt] = __builtin_amdgcn_mfma_f32_16x16x32_bf16(bfr[nt], afr[mt], acc[mt][nt], 0, 0, 0);
    }

    // ---- consume prefetch: cvt + write to other buffer (vmcnt wait lands here)
    if (pf) {
      unsigned short* Lw = (unsigned short*)lds[cur ^ 1];
#pragma unroll
      for (int i = 0; i < 8; ++i) {
        int row = r0 + 32 * i;
        ushort4 h;
        h.x = f2bf(g[i].x); h.y = f2bf(g[i].y); h.z = f2bf(g[i].z); h.w = f2bf(g[i].w);
        *(ushort4*)&Lw[row * LDA + c4 * 4] = h;
        rsum[i] += g[i].x + g[i].y + g[i].z + g[i].w;
      }
    }
    __syncthreads();
    cur ^= 1;
  }

  // D layout after swap: row (reg-quad) = gj-local, col = gi-local.
  // Value D[gj][gi] = S[gj][gi] = S[gi][gj]  ->  float4 store along gj.
  const int col = lane & 15;          // gi-local
  const int rq = (lane >> 4) * 4;     // gj-local quad base
  if (use_partial) {
    float* dst = partials + ((size_t)(b * gridDim.x + blockIdx.x)) * (CC * CC);
#pragma unroll
    for (int mt = 0; mt < 4; ++mt) {
      const int gi = wm * 64 + mt * 16 + col;
#pragma unroll
      for (int nt = 0; nt < 8; ++nt) {
        const int gj = wn * 128 + nt * 16 + rq;
        float4 v;
        v.x = acc[mt][nt][0]; v.y = acc[mt][nt][1];
        v.z = acc[mt][nt][2]; v.w = acc[mt][nt][3];
        *(float4*)&dst[(size_t)gi * CC + gj] = v;
      }
    }
  } else {
    float* Sb = S + (size_t)b * CC * CC;
#pragma unroll
    for (int mt = 0; mt < 4; ++mt)
#pragma unroll
      for (int nt = 0; nt < 8; ++nt)
#pragma unroll
        for (int r = 0; r < 4; ++r) {
          int gi = wm * 64 + mt * 16 + col;
          int gj = wn * 128 + nt * 16 + rq + r;
          atomicAdd(&Sb[(size_t)gi * CC + gj], acc[mt][nt][r]);
        }
  }

  // rowsums -> svec (small atomics; svec pre-zeroed)
  __syncthreads();
  float* ldsRS = (float*)lds[0];
  if (tid < 256) ldsRS[tid] = 0.f;
  __syncthreads();
#pragma unroll
  for (int i = 0; i < 8; ++i) atomicAdd(&ldsRS[r0 + 32 * i], rsum[i]);
  __syncthreads();
  if (tid < 256) atomicAdd(&svec[b * CC + tid], ldsRS[tid]);
}

// ---------------- partial reduction: S = sum over splits ---------------------
// float2 per thread: 65536 threads (256 x 256) = 4 waves/CU, 8-deep MLP.
__global__ __launch_bounds__(256) void nl3d_reduce(const float* __restrict__ partials,
                                                   float* __restrict__ S, int splits) {
  const int e = blockIdx.x * 256 + threadIdx.x;       // float2 index, 65536 total
  const int b = e >> 15;                              // 32768 float2 per batch
  const int off = e & 32767;
  const float2* p = (const float2*)partials;
  float2 a0 = {0, 0}, a1 = {0, 0}, a2 = {0, 0}, a3 = {0, 0};
  float2 a4 = {0, 0}, a5 = {0, 0}, a6 = {0, 0}, a7 = {0, 0};
  const size_t base = (size_t)b * splits * 32768 + off;
  for (int s = 0; s < splits; s += 8) {
    float2 v0 = p[base + (size_t)(s + 0) * 32768];
    float2 v1 = p[base + (size_t)(s + 1) * 32768];
    float2 v2 = p[base + (size_t)(s + 2) * 32768];
    float2 v3 = p[base + (size_t)(s + 3) * 32768];
    float2 v4 = p[base + (size_t)(s + 4) * 32768];
    float2 v5 = p[base + (size_t)(s + 5) * 32768];
    float2 v6 = p[base + (size_t)(s + 6) * 32768];
    float2 v7 = p[base + (size_t)(s + 7) * 32768];
    a0.x += v0.x; a0.y += v0.y;  a1.x += v1.x; a1.y += v1.y;
    a2.x += v2.x; a2.y += v2.y;  a3.x += v3.x; a3.y += v3.y;
    a4.x += v4.x; a4.y += v4.y;  a5.x += v5.x; a5.y += v5.y;
    a6.x += v6.x; a6.y += v6.y;  a7.x += v7.x; a7.y += v7.y;
  }
  float2 r;
  r.x = ((a0.x + a1.x) + (a2.x + a3.x)) + ((a4.x + a5.x) + (a6.x + a7.x));
  r.y = ((a0.y + a1.y) + (a2.y + a3.y)) + ((a4.y + a5.y) + (a6.y + a7.y));
  ((float2*)S)[e] = r;
}

// ---------------- fused b1+b2: P-row in LDS, kv out --------------------------
// Block (b,i): phase 1 computes P[i][:] = phi_w[i,:] @ S[b] into LDS (256 thr),
// phase 2 computes kv[b][i][:] (128 thr) reading g_w row-major directly
// (gwT transpose eliminated). u/v terms folded in per original b2 formula.
__global__ __launch_bounds__(256) void nl3d_b12(const float* __restrict__ phi_w,
                                                const float* __restrict__ S,
                                                const float* __restrict__ svec,
                                                const float* __restrict__ g_w,
                                                const float* __restrict__ phi_b,
                                                const float* __restrict__ g_b,
                                                float* __restrict__ kv) {
  __shared__ float Prow[CC];
  __shared__ float svl[CC];
  const int b = blockIdx.x >> 7, i = blockIdx.x & 127;
  const int d = threadIdx.x;
  const float* Sb = S + (size_t)b * CC * CC;
  const float* ph = phi_w + i * CC;
  float a0 = 0.f, a1 = 0.f, a2 = 0.f, a3 = 0.f;
  float a4 = 0.f, a5 = 0.f, a6 = 0.f, a7 = 0.f;
  for (int c = 0; c < CC; c += 8) {
    a0 += ph[c + 0] * Sb[(c + 0) * CC + d];
    a1 += ph[c + 1] * Sb[(c + 1) * CC + d];
    a2 += ph[c + 2] * Sb[(c + 2) * CC + d];
    a3 += ph[c + 3] * Sb[(c + 3) * CC + d];
    a4 += ph[c + 4] * Sb[(c + 4) * CC + d];
    a5 += ph[c + 5] * Sb[(c + 5) * CC + d];
    a6 += ph[c + 6] * Sb[(c + 6) * CC + d];
    a7 += ph[c + 7] * Sb[(c + 7) * CC + d];
  }
  Prow[d] = ((a0 + a1) + (a2 + a3)) + ((a4 + a5) + (a6 + a7));
  svl[d] = svec[b * CC + d];
  __syncthreads();

  if (d < CI) {
    const int j = d;
    const float* gr = g_w + (size_t)j * CC;     // row-major along inner dim
    float p0 = 0.f, p1 = 0.f, p2 = 0.f, p3 = 0.f;
    float v0 = 0.f, v1 = 0.f, v2 = 0.f, v3 = 0.f;
    float u0 = 0.f, u1 = 0.f, u2 = 0.f, u3 = 0.f;
    for (int c = 0; c < CC; c += 4) {
      float g0 = gr[c], g1 = gr[c + 1], g2 = gr[c + 2], g3 = gr[c + 3];
      p0 += Prow[c] * g0;     p1 += Prow[c + 1] * g1;
      p2 += Prow[c + 2] * g2; p3 += Prow[c + 3] * g3;
      v0 += svl[c] * g0;      v1 += svl[c + 1] * g1;
      v2 += svl[c + 2] * g2;  v3 += svl[c + 3] * g3;
      u0 += ph[c] * svl[c];       u1 += ph[c + 1] * svl[c + 1];
      u2 += ph[c + 2] * svl[c + 2]; u3 += ph[c + 3] * svl[c + 3];
    }
    float a = (p0 + p1) + (p2 + p3);
    float v = (v0 + v1) + (v2 + v3);
    float u = (u0 + u1) + (u2 + u3);
    kv[((size_t)b * CI + i) * CI + j] =
        a + u * g_b[j] + phi_b[i] * (v + (float)NN * g_b[j]);
  }
}

__global__ void nl3d_b3(const float* __restrict__ kv, const float* __restrict__ theta_w,
                        const float* __restrict__ theta_b, float* __restrict__ T2,
                        float* __restrict__ tb2) {
  int b = blockIdx.x >> 7, j = blockIdx.x & 127, c = threadIdx.x;
  const float* kvb = kv + (size_t)b * CI * CI;
  float a0 = 0.f, a1 = 0.f, a2 = 0.f, a3 = 0.f;
  for (int i = 0; i < CI; i += 4) {
    a0 += kvb[i * CI + j] * theta_w[i * CC + c];
    a1 += kvb[(i + 1) * CI + j] * theta_w[(i + 1) * CC + c];
    a2 += kvb[(i + 2) * CI + j] * theta_w[(i + 2) * CC + c];
    a3 += kvb[(i + 3) * CI + j] * theta_w[(i + 3) * CC + c];
  }
  T2[((size_t)b * CI + j) * CC + c] = (a0 + a1) + (a2 + a3);
  if (c == 0) {
    float t = 0.f;
    for (int i = 0; i < CI; ++i) t += kvb[i * CI + j] * theta_b[i];
    tb2[b * CI + j] = t;
  }
}

__global__ void nl3d_b4(const float* __restrict__ T2, const float* __restrict__ tb2,
                        const float* __restrict__ W_w, const float* __restrict__ W_b,
                        unsigned short* __restrict__ Mbf, float* __restrict__ cvec) {
  int b = blockIdx.x >> 8, o = blockIdx.x & 255, c = threadIdx.x;
  const float inv = 1.0f / (float)NN;
  const float* Wr = W_w + o * CI;
  float a0 = 0.f, a1 = 0.f, a2 = 0.f, a3 = 0.f;
  for (int j = 0; j < CI; j += 4) {
    a0 += Wr[j] * T2[((size_t)b * CI + j) * CC + c];
    a1 += Wr[j + 1] * T2[((size_t)b * CI + j + 1) * CC + c];
    a2 += Wr[j + 2] * T2[((size_t)b * CI + j + 2) * CC + c];
    a3 += Wr[j + 3] * T2[((size_t)b * CI + j + 3) * CC + c];
  }
  Mbf[((size_t)b * CC + o) * CC + c] = f2bf(((a0 + a1) + (a2 + a3)) * inv);
  if (c == 0) {
    float t = 0.f;
    for (int j = 0; j < CI; ++j) t += Wr[j] * tb2[b * CI + j];
    cvec[b * CC + o] = t * inv + W_b[o];
  }
}

// ---------------- Kernel C: out = x + M x + c (bf16 MFMA) --------------------
// v4: round-3 stage/MFMA (256 thr, hoisted loads, M-pipeline, unswapped
// operands) + LDS-BOUNCE EPILOGUE: after the MFMA loop xT is dead; each wave
// writes its acc into a stride-68 f32 buffer (conflict-free) and re-reads it
// row-contiguously. Epilogue VMEM: 16 ds_read_b128 + 16 float4 loads +
// 16 float4 stores per thread (vs 128 scalar ops), every quarter-wave =
// 4 consecutive full 64B lines in ONE row (round-4 lesson: lanes of a quarter
// must stay within a row or writes partial-line RMW-amplify).
__global__ __launch_bounds__(256) void nl3d_out(const float* __restrict__ x,
                                                const unsigned short* __restrict__ Mbf,
                                                const float* __restrict__ cvec,
                                                float* __restrict__ out) {
  __shared__ __align__(16) char smem[128 * LDSW * 4];   // 34816 B (>= 64*LDX*2)
  unsigned short* xT = (unsigned short*)smem;  // [n-col 0..63][k 0..255] bf16
  const int tid = threadIdx.x;
  const int lane = tid & 63;
  const int wv = tid >> 6;                  // out-channel group
  const int b = blockIdx.y;
  const int n0 = blockIdx.x * 64;

  const float* xb = x + (size_t)b * CC * NN;
  float* ob = out + (size_t)b * CC * NN;

  {   // stage x[0:256][n0:n0+64] -> transposed bf16 LDS (swizzled dword stores)
    const int c4 = tid & 15;
    const int t4 = tid >> 4;
    float4 f0[8], f1[8];
#pragma unroll
    for (int i = 0; i < 8; ++i) {
      int p = i * 16 + t4;                  // k row-pair 0..127 (= dword index)
      f0[i] = *(const float4*)(xb + (size_t)(2 * p) * NN + n0 + c4 * 4);
      f1[i] = *(const float4*)(xb + (size_t)(2 * p + 1) * NN + n0 + c4 * 4);
    }
#pragma unroll
    for (int i = 0; i < 8; ++i) {
      int p = i * 16 + t4;
      int ps = p ^ ((c4 & 7) << 2);         // swizzle: key = (row>>2)&7, row=c4*4+j
      float a0[4] = {f0[i].x, f0[i].y, f0[i].z, f0[i].w};
      float a1[4] = {f1[i].x, f1[i].y, f1[i].z, f1[i].w};
#pragma unroll
      for (int j = 0; j < 4; ++j) {
        unsigned pack = (unsigned)f2bf(a0[j]) | ((unsigned)f2bf(a1[j]) << 16);
        *(unsigned*)&xT[(c4 * 4 + j) * LDX + 2 * ps] = pack;
      }
    }
  }
  __syncthreads();

  f32x4 acc[4][4];
  const f32x4 zero4 = {0.f, 0.f, 0.f, 0.f};
#pragma unroll
  for (int i = 0; i < 4; ++i)
#pragma unroll
    for (int j = 0; j < 4; ++j) acc[i][j] = zero4;

  const int m = lane & 15;
  const int kg = (lane >> 4) * 8;
  const unsigned short* Mb = Mbf + (size_t)b * CC * CC;

  // software-pipeline the L2-warm M-fragment loads one kc ahead
  bf16x8 afr[4];
#pragma unroll
  for (int mt = 0; mt < 4; ++mt)
    afr[mt] = *(const bf16x8*)(Mb + (size_t)(wv * 64 + mt * 16 + m) * CC + kg);
#pragma unroll
  for (int kc = 0; kc < 8; ++kc) {
    bf16x8 curf[4];
#pragma unroll
    for (int mt = 0; mt < 4; ++mt) curf[mt] = afr[mt];
    if (kc < 7) {
#pragma unroll
      for (int mt = 0; mt < 4; ++mt)
        afr[mt] = *(const bf16x8*)(Mb + (size_t)(wv * 64 + mt * 16 + m) * CC + (kc + 1) * 32 + kg);
    }
    bf16x8 bfr[4];
#pragma unroll
    for (int nt = 0; nt < 4; ++nt) {
      int rr = nt * 16 + m;
      int d0 = (kc * 16 + (kg >> 1)) ^ (((rr >> 2) & 7) << 2);
      bfr[nt] = *(const bf16x8*)&xT[rr * LDX + 2 * d0];
    }
#pragma unroll
    for (int mt = 0; mt < 4; ++mt)
#pragma unroll
      for (int nt = 0; nt < 4; ++nt)
        acc[mt][nt] = __builtin_amdgcn_mfma_f32_16x16x32_bf16(curf[mt], bfr[nt], acc[mt][nt], 0, 0, 0);
  }

  // ---- LDS-bounce epilogue: acc quad is along o (rows). Write to f32 LDS,
  // re-read row-contiguous. Wave w uses rows [w*32, w*32+32) exclusively.
  float* eb = (float*)smem;
  const int colo = lane & 15;
  const int rq4 = (lane >> 4) * 4;
  const int frow = lane >> 4;          // 0..3
  const int fcol = (lane & 15) * 4;    // dword col in flush
#pragma unroll
  for (int h = 0; h < 2; ++h) {
    __syncthreads();   // h=0: all xT MFMA reads done; h=1: prior flush reads done
#pragma unroll
    for (int mi = 0; mi < 2; ++mi) {
      const int mt = 2 * h + mi;
      const int lrb = wv * 32 + mi * 16 + rq4;
#pragma unroll
      for (int nt = 0; nt < 4; ++nt)
#pragma unroll
        for (int r = 0; r < 4; ++r)
          eb[(lrb + r) * LDSW + nt * 16 + colo] = acc[mt][nt][r];
    }
    __syncthreads();   // cross-lane LDS visibility within (and across) waves
#pragma unroll
    for (int it = 0; it < 8; ++it) {
      const int lr = wv * 32 + it * 4 + frow;
      const int o  = wv * 64 + h * 32 + it * 4 + frow;
      float4 v = *(float4*)&eb[lr * LDSW + fcol];
      const float cv = cvec[b * CC + o];
      float4 xv = *(const float4*)(xb + (size_t)o * NN + n0 + fcol);
      float4 rr;
      rr.x = xv.x + v.x + cv;
      rr.y = xv.y + v.y + cv;
      rr.z = xv.z + v.z + cv;
      rr.w = xv.w + v.w + cv;
      *(float4*)(ob + (size_t)o * NN + n0 + fcol) = rr;   // exact fp32 residual
    }
  }
}

extern "C" void kernel_launch(void* const* d_in, const int* in_sizes, int n_in,
                              void* d_out, int out_size, void* d_ws, size_t ws_size,
                              hipStream_t stream) {
  const float* x       = (const float*)d_in[0];
  const float* g_w     = (const float*)d_in[1];
  const float* g_b     = (const float*)d_in[2];
  const float* theta_w = (const float*)d_in[3];
  const float* theta_b = (const float*)d_in[4];
  const float* phi_w   = (const float*)d_in[5];
  const float* phi_b   = (const float*)d_in[6];
  const float* W_w     = (const float*)d_in[7];
  const float* W_b     = (const float*)d_in[8];
  float* out = (float*)d_out;

  char* ws = (char*)d_ws;
  float* S    = (float*)(ws);                         // 2*256*256 f32 = 512 KiB
  float* svec = (float*)(ws + 524288);                // 2*256
  float* kv   = (float*)(ws + 919552);                // 2*128*128
  float* T2   = (float*)(ws + 1050624);               // 2*128*256
  float* tb2  = (float*)(ws + 1312768);               // 2*128
  unsigned short* Mbf = (unsigned short*)(ws + 1313792); // 2*256*256 bf16
  float* cvec = (float*)(ws + 1575936);               // 2*256
  float* partials = (float*)(ws + 2097152);           // NB*splits*256KB

  // pick largest power-of-2 split count whose partials fit in ws
  int splits = 0;
  for (int c = 128; c >= 8; c >>= 1) {
    if (2097152 + (size_t)NB * c * CC * CC * 4 <= ws_size) { splits = c; break; }
  }

  if (splits > 0) {
    hipMemsetAsync(svec, 0, 2048, stream);            // svec only (S via reduce)
    nl3d_syrk2<<<dim3(splits, NB), 512, 0, stream>>>(x, S, partials, svec,
                                                     NN / splits, 1);
    nl3d_reduce<<<256, 256, 0, stream>>>(partials, S, splits);
  } else {
    hipMemsetAsync(ws, 0, 526336, stream);            // S + svec (atomic accum)
    nl3d_syrk2<<<dim3(64, NB), 512, 0, stream>>>(x, S, (float*)ws, svec,
                                                 NN / 64, 0);
  }
  nl3d_b12<<<NB * CI, 256, 0, stream>>>(phi_w, S, svec, g_w, phi_b, g_b, kv);
  nl3d_b3<<<NB * CI, 256, 0, stream>>>(kv, theta_w, theta_b, T2, tb2);
  nl3d_b4<<<NB * CC, 256, 0, stream>>>(T2, tb2, W_w, W_b, Mbf, cvec);
  nl3d_out<<<dim3(NN / 64, NB), 256, 0, stream>>>(x, Mbf, cvec, out);
}